// Round 1
// baseline (303.302 us; speedup 1.0000x reference)
//
#include <hip/hip_runtime.h>

#define NN   120000
#define NP   120064   // 938 * 128, padded rows
#define EPSV 1e-5f

typedef __attribute__((ext_vector_type(8))) short          short8v;   // bf16 MFMA frag
typedef __attribute__((ext_vector_type(8))) unsigned short ushort8v;
typedef __attribute__((ext_vector_type(4))) unsigned short ushort4v;
typedef __attribute__((ext_vector_type(4))) float          f32x4;

__device__ __forceinline__ float b2f(unsigned short u) {
    union { unsigned int i; float f; } x; x.i = ((unsigned int)u) << 16; return x.f;
}
__device__ __forceinline__ unsigned short f2b(float f) {
    union { float f; unsigned int i; } x; x.f = f;
    unsigned int i = x.i + 0x7FFFu + ((x.i >> 16) & 1u);
    return (unsigned short)(i >> 16);
}

// ---------------------------------------------------------------------------
// K1: y1 = feat @ w1.T  (K=5), raw output (no BN), accumulate per-channel stats.
// 128 rows per block, 256 threads: c = tid&127, row-half = tid>>7.
// Pad rows (>=NN) get y=0 (contributes nothing to stats).
// ---------------------------------------------------------------------------
__global__ __launch_bounds__(256) void k1_kernel(
    const float* __restrict__ feat, const float* __restrict__ w1,
    unsigned short* __restrict__ y1, float* __restrict__ stat1)
{
    __shared__ float red[512];
    const int tid = threadIdx.x;
    const int c = tid & 127;
    const int rh = tid >> 7;
    const int rowbase = blockIdx.x * 128;

    float wr_[5];
#pragma unroll
    for (int k = 0; k < 5; ++k) wr_[k] = w1[c * 5 + k];

    float ls = 0.f, lq = 0.f;
#pragma unroll 4
    for (int i = 0; i < 64; ++i) {
        int row = rowbase + i * 2 + rh;
        float y = 0.f;
        if (row < NN) {
            const float* fp = feat + (size_t)row * 5;
            y = fp[0]*wr_[0] + fp[1]*wr_[1] + fp[2]*wr_[2] + fp[3]*wr_[3] + fp[4]*wr_[4];
        }
        y1[(size_t)row * 128 + c] = f2b(y);
        ls += y; lq += y * y;
    }
    red[tid] = ls; red[tid + 256] = lq;
    __syncthreads();
    if (tid < 128) {
        atomicAdd(&stat1[tid],       red[tid]       + red[tid + 128]);
        atomicAdd(&stat1[128 + tid], red[tid + 256] + red[tid + 384]);
    }
}

// ---------------------------------------------------------------------------
// GEMM with fused input-BN+relu and output stats accumulation.
// Y[row][c] = sum_k relu(X[row][k]*scl[k]+bia[k]) * W[c][k]
// Tile: 128 rows x 128 cols per block; 4 waves, 64x64 per wave; K chunks of 128.
// LDS XOR swizzle: byte_in_row ^= (row&7)<<4 (both write & read sides).
// ---------------------------------------------------------------------------
template<int KD>
__global__ __launch_bounds__(256) void gemm_bn_kernel(
    const unsigned short* __restrict__ X, const float* __restrict__ statsIn,
    const float* __restrict__ gIn, const float* __restrict__ bIn,
    const float* __restrict__ W, unsigned short* __restrict__ Y,
    float* __restrict__ statsOut, int coutTotal)
{
    __shared__ char lds[67584];
    char* As = lds;
    char* Bs = lds + 32768;
    float* scl = (float*)(lds + 65536);
    float* bia = (float*)(lds + 65536 + 1024);

    const int tid = threadIdx.x;
    const int rowbase = blockIdx.x * 128;
    const int cbase = blockIdx.y * 128;

    if (tid < KD) {
        float mean = statsIn[tid] * (1.0f / NN);
        float var  = statsIn[KD + tid] * (1.0f / NN) - mean * mean;
        float s    = gIn[tid] * rsqrtf(var + EPSV);
        scl[tid] = s;
        bia[tid] = bIn[tid] - mean * s;
    }
    __syncthreads();

    f32x4 acc[4][4] = {};

    const int l  = tid & 63;
    const int wv = tid >> 6;
    const int wr = wv >> 1, wc = wv & 1;
    const int lm = l & 15, lg = l >> 4;

#pragma unroll
    for (int kc = 0; kc < KD / 128; ++kc) {
        if (kc) __syncthreads();
        // ---- stage A (BN+relu applied, f32->bf16) ----
#pragma unroll
        for (int i = 0; i < 8; ++i) {
            int e = i * 256 + tid;           // 0..2047
            int row = e >> 4;                // 0..127
            int k8 = (e & 15) * 8;           // 0..120
            ushort8v v = *(const ushort8v*)(X + (size_t)(rowbase + row) * KD + kc * 128 + k8);
            int kg0 = kc * 128 + k8;
            f32x4 s0 = *(const f32x4*)(scl + kg0);
            f32x4 s1 = *(const f32x4*)(scl + kg0 + 4);
            f32x4 c0 = *(const f32x4*)(bia + kg0);
            f32x4 c1 = *(const f32x4*)(bia + kg0 + 4);
            ushort8v o;
#pragma unroll
            for (int j = 0; j < 4; ++j) {
                float f = fmaxf(b2f(v[j]) * s0[j] + c0[j], 0.f);
                o[j] = f2b(f);
            }
#pragma unroll
            for (int j = 0; j < 4; ++j) {
                float f = fmaxf(b2f(v[4 + j]) * s1[j] + c1[j], 0.f);
                o[4 + j] = f2b(f);
            }
            *(ushort8v*)(As + row * 256 + ((k8 * 2) ^ ((row & 7) << 4))) = o;
        }
        // ---- stage B (weights f32 -> bf16) ----
#pragma unroll
        for (int i = 0; i < 16; ++i) {
            int e = i * 256 + tid;           // 0..4095
            int c = e >> 5;                  // 0..127
            int k4 = (e & 31) * 4;           // 0..124
            f32x4 w = *(const f32x4*)(W + (size_t)(cbase + c) * KD + kc * 128 + k4);
            ushort4v p;
#pragma unroll
            for (int j = 0; j < 4; ++j) p[j] = f2b(w[j]);
            *(ushort4v*)(Bs + c * 256 + ((k4 * 2) ^ ((c & 7) << 4))) = p;
        }
        __syncthreads();
        // ---- MFMA ----
#pragma unroll
        for (int kk = 0; kk < 4; ++kk) {
            short8v a[4], b[4];
            int kb = (kk * 32 + lg * 8) * 2;
#pragma unroll
            for (int mi = 0; mi < 4; ++mi) {
                int r = wr * 64 + mi * 16 + lm;
                a[mi] = *(const short8v*)(As + r * 256 + (kb ^ ((r & 7) << 4)));
            }
#pragma unroll
            for (int ni = 0; ni < 4; ++ni) {
                int c = wc * 64 + ni * 16 + lm;
                b[ni] = *(const short8v*)(Bs + c * 256 + (kb ^ ((c & 7) << 4)));
            }
#pragma unroll
            for (int mi = 0; mi < 4; ++mi)
#pragma unroll
                for (int ni = 0; ni < 4; ++ni)
                    acc[mi][ni] = __builtin_amdgcn_mfma_f32_16x16x32_bf16(a[mi], b[ni], acc[mi][ni], 0, 0, 0);
        }
    }

    // ---- per-channel stats (masked to real rows) ----
#pragma unroll
    for (int ni = 0; ni < 4; ++ni) {
        float s = 0.f, q = 0.f;
#pragma unroll
        for (int mi = 0; mi < 4; ++mi)
#pragma unroll
            for (int r = 0; r < 4; ++r) {
                int rowg = rowbase + wr * 64 + mi * 16 + lg * 4 + r;
                float v = acc[mi][ni][r];
                v = (rowg < NN) ? v : 0.f;
                s += v; q += v * v;
            }
        s += __shfl_xor(s, 16); s += __shfl_xor(s, 32);
        q += __shfl_xor(q, 16); q += __shfl_xor(q, 32);
        if (lg == 0) {
            int cg = cbase + wc * 64 + ni * 16 + lm;
            atomicAdd(&statsOut[cg], s);
            atomicAdd(&statsOut[coutTotal + cg], q);
        }
    }

    // ---- C -> LDS -> coalesced global store (bf16) ----
    __syncthreads();
#pragma unroll
    for (int mi = 0; mi < 4; ++mi)
#pragma unroll
        for (int ni = 0; ni < 4; ++ni)
#pragma unroll
            for (int r = 0; r < 4; ++r) {
                int row = wr * 64 + mi * 16 + lg * 4 + r;
                int colb = (wc * 64 + ni * 16 + lm) * 2;
                *(unsigned short*)(lds + row * 256 + (colb ^ ((row & 7) << 4))) = f2b(acc[mi][ni][r]);
            }
    __syncthreads();
    {
        int row = tid >> 1;
        int hb = (tid & 1) * 128;   // byte base within row
        unsigned short* Yrow = Y + (size_t)(rowbase + row) * coutTotal + cbase + (hb >> 1);
#pragma unroll
        for (int j = 0; j < 8; ++j) {
            ushort8v v = *(const ushort8v*)(lds + row * 256 + ((hb + j * 16) ^ ((row & 7) << 4)));
            *(ushort8v*)(Yrow + j * 8) = v;
        }
    }
}

// ---------------------------------------------------------------------------
// K5: x5 = relu( BN4(y4) + relu(BN2(y2)) ); logits = x5 @ w_out.T + b_out
// 8 lanes per row (sub = lane&7 covers 16 channels), shfl-reduce over sub.
// ---------------------------------------------------------------------------
__global__ __launch_bounds__(256) void k5_kernel(
    const unsigned short* __restrict__ y2, const unsigned short* __restrict__ y4,
    const float* __restrict__ stat2, const float* __restrict__ g2, const float* __restrict__ b2,
    const float* __restrict__ stat4, const float* __restrict__ g4, const float* __restrict__ b4,
    const float* __restrict__ w_out, const float* __restrict__ b_out,
    float* __restrict__ out)
{
    __shared__ float wT[128 * 8];
    __shared__ float sc2[128], bi2[128], sc4[128], bi4[128], bo[8];
    const int tid = threadIdx.x;

    if (tid < 128) {
        float m2 = stat2[tid] * (1.0f / NN);
        float v2 = stat2[128 + tid] * (1.0f / NN) - m2 * m2;
        float s2 = g2[tid] * rsqrtf(v2 + EPSV);
        sc2[tid] = s2; bi2[tid] = b2[tid] - m2 * s2;
        float m4 = stat4[tid] * (1.0f / NN);
        float v4 = stat4[128 + tid] * (1.0f / NN) - m4 * m4;
        float s4 = g4[tid] * rsqrtf(v4 + EPSV);
        sc4[tid] = s4; bi4[tid] = b4[tid] - m4 * s4;
    }
    for (int i = tid; i < 1024; i += 256) wT[i] = w_out[(i & 7) * 128 + (i >> 3)];
    if (tid < 8) bo[tid] = b_out[tid];
    __syncthreads();

    const int l = tid & 63, wv = tid >> 6;
    const int sub = l & 7, rl = l >> 3;
    const int row = blockIdx.x * 32 + wv * 8 + rl;   // grid sized so row < NN always

    const ushort8v* p2 = (const ushort8v*)(y2 + (size_t)row * 128 + sub * 16);
    const ushort8v* p4 = (const ushort8v*)(y4 + (size_t)row * 128 + sub * 16);

    float p[8];
#pragma unroll
    for (int o = 0; o < 8; ++o) p[o] = 0.f;

#pragma unroll
    for (int jj = 0; jj < 2; ++jj) {
        ushort8v a2 = p2[jj];
        ushort8v a4 = p4[jj];
#pragma unroll
        for (int e = 0; e < 8; ++e) {
            int c = sub * 16 + jj * 8 + e;
            float i2 = fmaxf(b2f(a2[e]) * sc2[c] + bi2[c], 0.f);
            float x4 = b2f(a4[e]) * sc4[c] + bi4[c];
            float x5 = fmaxf(x4 + i2, 0.f);
            const f32x4* wp = (const f32x4*)(wT + c * 8);
            f32x4 wa = wp[0], wb = wp[1];
            p[0] += x5 * wa[0]; p[1] += x5 * wa[1]; p[2] += x5 * wa[2]; p[3] += x5 * wa[3];
            p[4] += x5 * wb[0]; p[5] += x5 * wb[1]; p[6] += x5 * wb[2]; p[7] += x5 * wb[3];
        }
    }
#pragma unroll
    for (int o = 0; o < 8; ++o) {
        p[o] += __shfl_xor(p[o], 1);
        p[o] += __shfl_xor(p[o], 2);
        p[o] += __shfl_xor(p[o], 4);
    }
    out[(size_t)row * 8 + sub] = p[sub] + bo[sub];
}

// ---------------------------------------------------------------------------
extern "C" void kernel_launch(void* const* d_in, const int* in_sizes, int n_in,
                              void* d_out, int out_size, void* d_ws, size_t ws_size,
                              hipStream_t stream)
{
    const float* feat  = (const float*)d_in[0];
    // d_in[1] coord, d_in[2] knn_idx, d_in[3] offset: dead code in reference
    const float* w1    = (const float*)d_in[4];
    const float* g1    = (const float*)d_in[5];
    const float* b1    = (const float*)d_in[6];
    const float* w2    = (const float*)d_in[7];
    const float* g2    = (const float*)d_in[8];
    const float* b2    = (const float*)d_in[9];
    const float* w3    = (const float*)d_in[10];
    const float* g3    = (const float*)d_in[11];
    const float* b3    = (const float*)d_in[12];
    const float* w4    = (const float*)d_in[13];
    const float* g4    = (const float*)d_in[14];
    const float* b4    = (const float*)d_in[15];
    const float* w_out = (const float*)d_in[16];
    const float* b_out = (const float*)d_in[17];

    char* ws = (char*)d_ws;
    const size_t sz128 = (size_t)NP * 128 * 2;   // bf16 N x 128
    const size_t sz256 = (size_t)NP * 256 * 2;   // bf16 N x 256
    unsigned short* y1 = (unsigned short*)(ws);
    unsigned short* y2 = (unsigned short*)(ws + sz128);
    unsigned short* y3 = (unsigned short*)(ws + 2 * sz128);
    unsigned short* y4 = (unsigned short*)(ws + 2 * sz128 + sz256);
    float* stats       = (float*)(ws + 3 * sz128 + sz256);
    float* stat1 = stats;          // 2*128
    float* stat2 = stats + 256;    // 2*128
    float* stat3 = stats + 512;    // 2*256
    float* stat4 = stats + 1024;   // 2*128

    hipMemsetAsync(stats, 0, 1280 * sizeof(float), stream);

    k1_kernel<<<dim3(938), 256, 0, stream>>>(feat, w1, y1, stat1);
    gemm_bn_kernel<128><<<dim3(938, 1), 256, 0, stream>>>(y1, stat1, g1, b1, w2, y2, stat2, 128);
    gemm_bn_kernel<128><<<dim3(938, 2), 256, 0, stream>>>(y2, stat2, g2, b2, w3, y3, stat3, 256);
    gemm_bn_kernel<256><<<dim3(938, 1), 256, 0, stream>>>(y3, stat3, g3, b3, w4, y4, stat4, 128);
    k5_kernel<<<dim3(3750), 256, 0, stream>>>(y2, y4, stat2, g2, b2, stat4, g4, b4,
                                              w_out, b_out, (float*)d_out);
}